// Round 1
// baseline (472.639 us; speedup 1.0000x reference)
//
#include <hip/hip_runtime.h>
#include <hip/hip_bf16.h>

typedef unsigned short ushort_t;
typedef __attribute__((ext_vector_type(8))) short short8;
typedef __attribute__((ext_vector_type(8))) __bf16 bf16x8;
typedef __attribute__((ext_vector_type(4))) float f32x4;

#define LQS 4096
#define LKS 4096
#define NH 16
#define HD 64
#define DIN 1024
static constexpr float TAU_S = 0.125f;  // 1/sqrt(64)

__device__ __forceinline__ ushort_t f32_to_bf16(float x) {
  union { float f; unsigned u; } v; v.f = x;
  unsigned r = v.u + 0x7FFF + ((v.u >> 16) & 1);
  return (ushort_t)(r >> 16);
}

__device__ __forceinline__ void gld_lds16(const void* g, void* l) {
  __builtin_amdgcn_global_load_lds((const __attribute__((address_space(1))) void*)g,
                                   (__attribute__((address_space(3))) void*)l, 16, 0, 0);
}

__device__ __forceinline__ f32x4 mfma16(bf16x8 a, bf16x8 b, f32x4 c) {
  return __builtin_amdgcn_mfma_f32_16x16x32_bf16(a, b, c, 0, 0, 0);
}

// ---------------- convert f32 -> bf16 (8 elems/thread) ----------------
__global__ void cvt_kernel(const float* __restrict__ src, ushort_t* __restrict__ dst, int n) {
  int i = (blockIdx.x * 256 + threadIdx.x) * 8;
  if (i + 8 > n) return;
  float4 a = *(const float4*)(src + i);
  float4 b = *(const float4*)(src + i + 4);
  short8 o;
  o[0] = (short)f32_to_bf16(a.x); o[1] = (short)f32_to_bf16(a.y);
  o[2] = (short)f32_to_bf16(a.z); o[3] = (short)f32_to_bf16(a.w);
  o[4] = (short)f32_to_bf16(b.x); o[5] = (short)f32_to_bf16(b.y);
  o[6] = (short)f32_to_bf16(b.z); o[7] = (short)f32_to_bf16(b.w);
  *(short8*)(dst + i) = o;
}

// ---------------- transpose + convert W [1024][1024] f32 -> Wt bf16 ----------------
__global__ void transpose_w(const float* __restrict__ W, ushort_t* __restrict__ Wt) {
  __shared__ float tile[64][65];
  const int t = threadIdx.x;
  const int k0 = blockIdx.y * 64, n0 = blockIdx.x * 64;
#pragma unroll
  for (int i = 0; i < 16; ++i) {
    int idx = i * 256 + t;
    int r = idx >> 6, c = idx & 63;
    tile[r][c] = W[(size_t)(k0 + r) * DIN + n0 + c];
  }
  __syncthreads();
#pragma unroll
  for (int i = 0; i < 16; ++i) {
    int idx = i * 256 + t;
    int r = idx >> 6, c = idx & 63;  // r: n-local, c: k-local
    Wt[(size_t)(n0 + r) * DIN + k0 + c] = f32_to_bf16(tile[c][r]);
  }
}

// ---------------- transpose vh [4096][16*64] -> vt [16][64][4096] ----------------
__global__ void transpose_v(const ushort_t* __restrict__ vh, ushort_t* __restrict__ vt) {
  __shared__ ushort_t tile[64][65];
  const int t = threadIdx.x;
  const int k0 = blockIdx.x * 64, h = blockIdx.y;
#pragma unroll
  for (int i = 0; i < 16; ++i) {
    int idx = i * 256 + t;
    int r = idx >> 6, c = idx & 63;  // r: k-local, c: x
    tile[r][c] = vh[(size_t)(k0 + r) * DIN + h * HD + c];
  }
  __syncthreads();
#pragma unroll
  for (int i = 0; i < 16; ++i) {
    int idx = i * 256 + t;
    int r = idx >> 6, c = idx & 63;  // r: x, c: k-local
    vt[((size_t)h * HD + r) * (size_t)LKS + k0 + c] = tile[c][r];
  }
}

// ---------------- NT GEMM: C[m][n] = scale*(sum_k A[m][k]*Bt[n][k] + bias[n]) ----------------
// 128x128 tile, BK=64, 4 waves (2x2), per-wave 64x64 via 4x4 frags of 16x16x32.
template <bool OUT_F32>
__launch_bounds__(256, 2)
__global__ void gemm_nt(const ushort_t* __restrict__ A, const ushort_t* __restrict__ Bt,
                        const float* __restrict__ bias, void* __restrict__ Cout,
                        int M, int N, int K, float scale) {
  __shared__ __align__(16) ushort_t Alds[128 * 64];
  __shared__ __align__(16) ushort_t Blds[128 * 64];
  const int t = threadIdx.x, wave = t >> 6, lane = t & 63;
  const int l15 = lane & 15, lg = lane >> 4;
  const int m0 = blockIdx.y * 128, n0 = blockIdx.x * 128;
  const int wr = wave >> 1, wc = wave & 1;
  f32x4 acc[4][4];
#pragma unroll
  for (int i = 0; i < 4; ++i)
#pragma unroll
    for (int j = 0; j < 4; ++j) acc[i][j] = (f32x4){0.f, 0.f, 0.f, 0.f};

  for (int tk = 0; tk < K / 64; ++tk) {
#pragma unroll
    for (int c = 0; c < 4; ++c) {
      int chunk = wave * 4 + c;
      int row = chunk * 8 + (lane >> 3);
      int ss = (lane & 7) ^ (row & 7);
      gld_lds16(A + (size_t)(m0 + row) * K + tk * 64 + ss * 8, (char*)Alds + chunk * 1024);
      gld_lds16(Bt + (size_t)(n0 + row) * K + tk * 64 + ss * 8, (char*)Blds + chunk * 1024);
    }
    __syncthreads();
#pragma unroll
    for (int kk = 0; kk < 2; ++kk) {
      bf16x8 a[4], b[4];
#pragma unroll
      for (int i = 0; i < 4; ++i) {
        int ra = wr * 64 + i * 16 + l15;
        a[i] = *(const bf16x8*)((const char*)Alds + ra * 128 + ((((kk * 4 + lg) << 4)) ^ ((ra & 7) << 4)));
        int rb = wc * 64 + i * 16 + l15;
        b[i] = *(const bf16x8*)((const char*)Blds + rb * 128 + ((((kk * 4 + lg) << 4)) ^ ((rb & 7) << 4)));
      }
#pragma unroll
      for (int mi = 0; mi < 4; ++mi)
#pragma unroll
        for (int ni = 0; ni < 4; ++ni)
          acc[mi][ni] = mfma16(a[mi], b[ni], acc[mi][ni]);
    }
    __syncthreads();
  }
#pragma unroll
  for (int ni = 0; ni < 4; ++ni) {
    int coln = n0 + wc * 64 + ni * 16 + l15;
    float bv = bias[coln];
#pragma unroll
    for (int mi = 0; mi < 4; ++mi) {
#pragma unroll
      for (int r = 0; r < 4; ++r) {
        int rowm = m0 + wr * 64 + mi * 16 + lg * 4 + r;
        float v = (acc[mi][ni][r] + bv) * scale;
        if (OUT_F32)
          ((float*)Cout)[(size_t)rowm * N + coln] = v;
        else
          ((ushort_t*)Cout)[(size_t)rowm * N + coln] = f32_to_bf16(v);
      }
    }
  }
}

// ---------------- fused attention ----------------
// grid: (LQ/64, NH). block 256 (4 waves), wave w owns Q rows [q0+16w, q0+16w+16).
// pass 1: rowsums of exp(S); pass 2: recompute S, write att=exp*recip (f32), PV via LDS P.
__launch_bounds__(256, 2)
__global__ void attn_kernel(const ushort_t* __restrict__ qh, const ushort_t* __restrict__ kh,
                            const ushort_t* __restrict__ vt, float* __restrict__ att,
                            ushort_t* __restrict__ ctx) {
  __shared__ __align__(16) ushort_t Klds[64 * 64];
  __shared__ __align__(16) ushort_t Vlds[64 * 64];
  __shared__ __align__(16) ushort_t Plds[64 * 64];
  const int t = threadIdx.x, wave = t >> 6, lane = t & 63;
  const int l15 = lane & 15, lg = lane >> 4;
  const int h = blockIdx.y;
  const int q0 = blockIdx.x * 64;

  bf16x8 qa[2];
  {
    int row = q0 + wave * 16 + l15;
    const ushort_t* qp = qh + (size_t)row * DIN + h * HD + lg * 8;
    qa[0] = *(const bf16x8*)(qp);
    qa[1] = *(const bf16x8*)(qp + 32);
  }

  float rs[4] = {0.f, 0.f, 0.f, 0.f};
  // ---- pass 1: row sums ----
  for (int tk = 0; tk < LKS / 64; ++tk) {
#pragma unroll
    for (int c = 0; c < 2; ++c) {
      int chunk = wave * 2 + c;
      int row = chunk * 8 + (lane >> 3);
      int ss = (lane & 7) ^ (row & 7);
      gld_lds16(kh + (size_t)(tk * 64 + row) * DIN + h * HD + ss * 8, (char*)Klds + chunk * 1024);
    }
    __syncthreads();
#pragma unroll
    for (int ct = 0; ct < 4; ++ct) {
      f32x4 acc = (f32x4){0.f, 0.f, 0.f, 0.f};
#pragma unroll
      for (int kk = 0; kk < 2; ++kk) {
        int row = ct * 16 + l15;
        bf16x8 kb = *(const bf16x8*)((const char*)Klds + row * 128 + ((((kk * 4 + lg) << 4)) ^ ((row & 7) << 4)));
        acc = mfma16(qa[kk], kb, acc);
      }
#pragma unroll
      for (int r = 0; r < 4; ++r) rs[r] += __expf(acc[r]);
    }
    __syncthreads();
  }
#pragma unroll
  for (int m = 1; m < 16; m <<= 1) {
#pragma unroll
    for (int r = 0; r < 4; ++r) rs[r] += __shfl_xor(rs[r], m, 64);
  }
  float recip[4];
#pragma unroll
  for (int r = 0; r < 4; ++r) recip[r] = 1.0f / rs[r];

  // ---- pass 2: att write + PV ----
  f32x4 cacc[4];
#pragma unroll
  for (int x = 0; x < 4; ++x) cacc[x] = (f32x4){0.f, 0.f, 0.f, 0.f};
  float* atth = att + ((size_t)h << 24);

  for (int tk = 0; tk < LKS / 64; ++tk) {
#pragma unroll
    for (int c = 0; c < 2; ++c) {
      int chunk = wave * 2 + c;
      int row = chunk * 8 + (lane >> 3);
      int ss = (lane & 7) ^ (row & 7);
      gld_lds16(kh + (size_t)(tk * 64 + row) * DIN + h * HD + ss * 8, (char*)Klds + chunk * 1024);
      gld_lds16(vt + ((size_t)h * HD + row) * (size_t)LKS + tk * 64 + ss * 8, (char*)Vlds + chunk * 1024);
    }
    __syncthreads();
#pragma unroll
    for (int ct = 0; ct < 4; ++ct) {
      f32x4 acc = (f32x4){0.f, 0.f, 0.f, 0.f};
#pragma unroll
      for (int kk = 0; kk < 2; ++kk) {
        int row = ct * 16 + l15;
        bf16x8 kb = *(const bf16x8*)((const char*)Klds + row * 128 + ((((kk * 4 + lg) << 4)) ^ ((row & 7) << 4)));
        acc = mfma16(qa[kk], kb, acc);
      }
#pragma unroll
      for (int r = 0; r < 4; ++r) {
        float p = __expf(acc[r]) * recip[r];
        int rowq = q0 + wave * 16 + lg * 4 + r;
        int col = tk * 64 + ct * 16 + l15;
        atth[((size_t)rowq << 12) + col] = p;
        int R = wave * 16 + lg * 4 + r;
        int byte = R * 128 + ((ct * 32 + l15 * 2) ^ ((R & 7) << 4));
        *(ushort_t*)((char*)Plds + byte) = f32_to_bf16(p);
      }
    }
    // PV: ctx[q][x] += sum_k P[q][k] * V[k][x]
    bf16x8 pa[2];
#pragma unroll
    for (int kk = 0; kk < 2; ++kk) {
      int R = wave * 16 + l15;
      pa[kk] = *(const bf16x8*)((const char*)Plds + R * 128 + ((((kk * 4 + lg) << 4)) ^ ((R & 7) << 4)));
    }
#pragma unroll
    for (int x = 0; x < 4; ++x) {
#pragma unroll
      for (int kk = 0; kk < 2; ++kk) {
        int rv = x * 16 + l15;
        bf16x8 vb = *(const bf16x8*)((const char*)Vlds + rv * 128 + ((((kk * 4 + lg) << 4)) ^ ((rv & 7) << 4)));
        cacc[x] = mfma16(pa[kk], vb, cacc[x]);
      }
    }
    __syncthreads();
  }
#pragma unroll
  for (int x = 0; x < 4; ++x) {
#pragma unroll
    for (int r = 0; r < 4; ++r) {
      int rowq = q0 + wave * 16 + lg * 4 + r;
      int col = h * HD + x * 16 + l15;
      ctx[(size_t)rowq * DIN + col] = f32_to_bf16(cacc[x][r]);
    }
  }
}

extern "C" void kernel_launch(void* const* d_in, const int* in_sizes, int n_in,
                              void* d_out, int out_size, void* d_ws, size_t ws_size,
                              hipStream_t stream) {
  const float* q = (const float*)d_in[0];
  const float* k = (const float*)d_in[1];
  const float* v = (const float*)d_in[2];
  const float* Wq = (const float*)d_in[3];
  const float* bq = (const float*)d_in[4];
  const float* Wk = (const float*)d_in[5];
  const float* bk = (const float*)d_in[6];
  const float* Wv = (const float*)d_in[7];
  const float* bv = (const float*)d_in[8];
  const float* Wo = (const float*)d_in[9];
  const float* bo = (const float*)d_in[10];

  float* out = (float*)d_out;
  float* att = out + (size_t)LQS * DIN;

  char* ws = (char*)d_ws;
  ushort_t* qhb = (ushort_t*)(ws + (size_t)0);
  ushort_t* khb = (ushort_t*)(ws + ((size_t)8 << 20));
  ushort_t* vhb = (ushort_t*)(ws + ((size_t)16 << 20));
  ushort_t* vtb = (ushort_t*)(ws + ((size_t)24 << 20));
  ushort_t* ctx = (ushort_t*)(ws + ((size_t)32 << 20));
  ushort_t* qb = (ushort_t*)(ws + ((size_t)40 << 20));
  ushort_t* kb = (ushort_t*)(ws + ((size_t)48 << 20));
  ushort_t* vb = (ushort_t*)(ws + ((size_t)56 << 20));
  ushort_t* Wqt = (ushort_t*)(ws + ((size_t)64 << 20));
  ushort_t* Wkt = (ushort_t*)(ws + ((size_t)66 << 20));
  ushort_t* Wvt = (ushort_t*)(ws + ((size_t)68 << 20));
  ushort_t* Wot = (ushort_t*)(ws + ((size_t)70 << 20));

  const int n = LQS * DIN;  // 4,194,304
  cvt_kernel<<<n / 8 / 256, 256, 0, stream>>>(q, qb, n);
  cvt_kernel<<<n / 8 / 256, 256, 0, stream>>>(k, kb, n);
  cvt_kernel<<<n / 8 / 256, 256, 0, stream>>>(v, vb, n);

  dim3 tg(16, 16);
  transpose_w<<<tg, 256, 0, stream>>>(Wq, Wqt);
  transpose_w<<<tg, 256, 0, stream>>>(Wk, Wkt);
  transpose_w<<<tg, 256, 0, stream>>>(Wv, Wvt);
  transpose_w<<<tg, 256, 0, stream>>>(Wo, Wot);

  dim3 gg(DIN / 128, LQS / 128);  // (8, 32)
  gemm_nt<false><<<gg, 256, 0, stream>>>(qb, Wqt, bq, qhb, LQS, DIN, DIN, TAU_S);
  gemm_nt<false><<<gg, 256, 0, stream>>>(kb, Wkt, bk, khb, LQS, DIN, DIN, 1.0f);
  gemm_nt<false><<<gg, 256, 0, stream>>>(vb, Wvt, bv, vhb, LQS, DIN, DIN, 1.0f);

  transpose_v<<<dim3(64, 16), 256, 0, stream>>>(vhb, vtb);

  attn_kernel<<<dim3(LQS / 64, NH), 256, 0, stream>>>(qhb, khb, vtb, att, ctx);

  gemm_nt<true><<<gg, 256, 0, stream>>>(ctx, Wot, bo, out, LQS, DIN, DIN, 1.0f);
}